// Round 11
// baseline (250.008 us; speedup 1.0000x reference)
//
#include <hip/hip_runtime.h>

// B=2, S=2048, D=1024, H=16, DK=64. Inputs fp32 dict-order, output fp32.
// Round 11: fast GEMMs in both ws worlds (5-region rotation fits 40 MB);
// LDS-transpose coalesced epilogue for V^T (mode 2); packed-f32 softmax.

typedef __attribute__((ext_vector_type(8))) __bf16 bf16x8;
typedef __attribute__((ext_vector_type(4))) __bf16 bf16x4;
typedef __attribute__((ext_vector_type(8))) float f32x8;
typedef __attribute__((ext_vector_type(4))) float f32x4;

#define MFMA16 __builtin_amdgcn_mfma_f32_16x16x32_bf16

union Bf8 { bf16x8 v; __bf16 e[8]; };

__device__ inline f32x4 zero4() { f32x4 z; z[0]=z[1]=z[2]=z[3]=0.f; return z; }

__device__ inline void load_lds16(const void* g, void* l) {
    __builtin_amdgcn_global_load_lds(
        (const __attribute__((address_space(1))) unsigned int*)g,
        (__attribute__((address_space(3))) unsigned int*)l, 16, 0, 0);
}

// ---------------------------------------------------------------------------
// Fused prep. z<4: transpose+convert weight z -> WT[n][k]. z>=4: flat fp32->
// bf16 convert of activation z-4 into d{0,1,2}. grid (32,32,Z), block 256.
// ---------------------------------------------------------------------------
__global__ __launch_bounds__(256) void prep_all(
        const float* __restrict__ w0, const float* __restrict__ w1,
        const float* __restrict__ w2, const float* __restrict__ w3,
        const float* __restrict__ x0, const float* __restrict__ x1,
        const float* __restrict__ x2,
        __bf16* __restrict__ wt, __bf16* __restrict__ d0,
        __bf16* __restrict__ d1, __bf16* __restrict__ d2) {
    const int z = blockIdx.z;
    const int t = threadIdx.x;
    if (z < 4) {
        const float* src = z == 0 ? w0 : z == 1 ? w1 : z == 2 ? w2 : w3;
        __bf16* dst = wt + (size_t)z * 1048576;
        __shared__ float tile[32][33];
        const int tc = t & 31, tr = t >> 5;
        const int r0 = blockIdx.y * 32, c0 = blockIdx.x * 32;
#pragma unroll
        for (int i = 0; i < 4; i++) {
            int r = tr + i * 8;
            tile[r][tc] = src[(size_t)(r0 + r) * 1024 + c0 + tc];
        }
        __syncthreads();
#pragma unroll
        for (int i = 0; i < 4; i++) {
            int r = tr + i * 8;
            dst[(size_t)(c0 + r) * 1024 + r0 + tc] = (__bf16)tile[tc][r];
        }
    } else {
        const float* src = z == 4 ? x0 : z == 5 ? x1 : x2;
        __bf16* dst = z == 4 ? d0 : z == 5 ? d1 : d2;
        int bid = blockIdx.y * 32 + blockIdx.x;
        size_t g = ((size_t)bid * 256 + t) * 16;
#pragma unroll
        for (int h = 0; h < 2; h++) {
            f32x8 a = *(const f32x8*)&src[g + h * 8];
            Bf8 tmp;
#pragma unroll
            for (int j = 0; j < 8; j++) tmp.e[j] = (__bf16)a[j];
            *(bf16x8*)&dst[g + h * 8] = tmp.v;
        }
    }
}

// ---------------------------------------------------------------------------
// FAST GEMM core: async global_load_lds(16B), XOR-swizzled LDS (stride 64,
// block cb at pc = cb ^ (row&7)). MODE 0: row-major fp32 out; MODE 1: Q/K
// head layout; MODE 2: V^T head layout with LDS-transpose coalesced stores.
// ---------------------------------------------------------------------------
template <int MODE, typename OutT>
__device__ inline void gemm_fast_core(const __bf16* __restrict__ A,
                                      const __bf16* __restrict__ Bt,
                                      const float* __restrict__ bias,
                                      OutT* __restrict__ out, float scale) {
    __shared__ __bf16 smem[16384];
    __bf16* As = smem;
    __bf16* Bs = smem + 8192;
    const int t = threadIdx.x;
    const int wave = t >> 6, lane = t & 63, lm = lane & 15, quad = lane >> 4;
    const int m0 = blockIdx.y * 128, n0 = blockIdx.x * 128;
    const int wm = (wave >> 1) * 64, wn = (wave & 1) * 64;

    f32x4 acc[4][4];
#pragma unroll
    for (int i = 0; i < 4; i++)
#pragma unroll
        for (int j = 0; j < 4; j++) acc[i][j] = zero4();

    for (int k0 = 0; k0 < 1024; k0 += 64) {
#pragma unroll
        for (int i = 0; i < 4; i++) {
            int s = i * 256 + t;
            int row = s >> 3, cb = (s & 7) ^ (row & 7);
            size_t goff = (size_t)row * 1024 + k0 + cb * 8;
            load_lds16(&A[(size_t)m0 * 1024 + goff],
                       &As[(size_t)(i * 256 + wave * 64) * 8]);
            load_lds16(&Bt[(size_t)n0 * 1024 + goff],
                       &Bs[(size_t)(i * 256 + wave * 64) * 8]);
        }
        __syncthreads();
#pragma unroll
        for (int ks = 0; ks < 2; ks++) {
            bf16x8 af[4], bfr[4];
#pragma unroll
            for (int mt = 0; mt < 4; mt++)
                af[mt] = *(const bf16x8*)&As[(wm + mt * 16 + lm) * 64 +
                                             (((ks * 4 + quad) ^ (lm & 7)) * 8)];
#pragma unroll
            for (int nt = 0; nt < 4; nt++)
                bfr[nt] = *(const bf16x8*)&Bs[(wn + nt * 16 + lm) * 64 +
                                              (((ks * 4 + quad) ^ (lm & 7)) * 8)];
#pragma unroll
            for (int mt = 0; mt < 4; mt++)
#pragma unroll
                for (int nt = 0; nt < 4; nt++)
                    acc[mt][nt] = MFMA16(af[mt], bfr[nt], acc[mt][nt], 0, 0, 0);
        }
        __syncthreads();
    }

    float bv4[4];
#pragma unroll
    for (int nt = 0; nt < 4; nt++) bv4[nt] = bias[n0 + wn + nt * 16 + lm];

    if (MODE == 2) {
        // acc -> swizzled smem Tr[c][r] at c*128 + (r ^ (8*(c&15))), then
        // b128 coalesced stores along s. (last loop iter ended in barrier)
#pragma unroll
        for (int mt = 0; mt < 4; mt++)
#pragma unroll
            for (int r = 0; r < 4; r++) {
                int rr = wm + mt * 16 + quad * 4 + r;
#pragma unroll
                for (int nt = 0; nt < 4; nt++) {
                    int c = wn + nt * 16 + lm;
                    smem[c * 128 + (rr ^ (8 * (c & 15)))] =
                        (__bf16)((acc[mt][nt][r] + bv4[nt]) * scale);
                }
            }
        __syncthreads();
        const int b = m0 >> 11;
#pragma unroll
        for (int it = 0; it < 8; it++) {
            int g = it * 256 + t;
            int c = g >> 4, gr = g & 15;
            bf16x8 v = *(const bf16x8*)&smem[c * 128 + ((gr * 8) ^ (8 * (c & 15)))];
            int col = n0 + c, hh = col >> 6, dk = col & 63;
            int sglob = (m0 & 2047) + gr * 8;
            size_t idx = (size_t)(b * 16 + hh) * 131072 + (size_t)dk * 2048 + sglob;
            *(bf16x8*)&out[idx] = v;
        }
    } else {
#pragma unroll
        for (int mt = 0; mt < 4; mt++) {
#pragma unroll
            for (int r = 0; r < 4; r++) {
                int row = m0 + wm + mt * 16 + quad * 4 + r;
#pragma unroll
                for (int nt = 0; nt < 4; nt++) {
                    int col = n0 + wn + nt * 16 + lm;
                    float val = (acc[mt][nt][r] + bv4[nt]) * scale;
                    size_t idx;
                    if (MODE == 0) {
                        idx = (size_t)row * 1024 + col;
                    } else {
                        int b = row >> 11, s = row & 2047, hh = col >> 6, dk = col & 63;
                        idx = (size_t)(b * 16 + hh) * 131072 + (size_t)s * 64 + dk;
                    }
                    out[idx] = (OutT)val;
                }
            }
        }
    }
}

// big path: fused QKV fast
__global__ __launch_bounds__(256) void proj_fast3(
        const __bf16* __restrict__ Xb, const __bf16* __restrict__ WT,
        const float* __restrict__ bq, const float* __restrict__ bk,
        const float* __restrict__ bv,
        __bf16* __restrict__ Q, __bf16* __restrict__ K, __bf16* __restrict__ Vt) {
    int z = blockIdx.z;
    if (z == 0)
        gemm_fast_core<1, __bf16>(Xb, WT, bq, Q, 0.125f);
    else if (z == 1)
        gemm_fast_core<1, __bf16>(Xb + 4194304, WT + 1048576, bk, K, 1.f);
    else
        gemm_fast_core<2, __bf16>(Xb + 8388608, WT + 2097152, bv, Vt, 1.f);
}

// small path: fused Q+V fast
__global__ __launch_bounds__(256) void proj_qv(
        const __bf16* __restrict__ Xq, const __bf16* __restrict__ Xv,
        const __bf16* __restrict__ WT,
        const float* __restrict__ bq, const float* __restrict__ bv,
        __bf16* __restrict__ Q, __bf16* __restrict__ Vt) {
    if (blockIdx.z == 0)
        gemm_fast_core<1, __bf16>(Xq, WT, bq, Q, 0.125f);
    else
        gemm_fast_core<2, __bf16>(Xv, WT + 2097152, bv, Vt, 1.f);
}

__global__ __launch_bounds__(256) void out_proj_fast(
        const __bf16* __restrict__ A, const __bf16* __restrict__ Bt,
        const float* __restrict__ bias, float* __restrict__ out) {
    gemm_fast_core<0, float>(A, Bt, bias, out, 1.f);
}

// ---------------------------------------------------------------------------
// Slow GEMM (fp32 A VGPR-staged) — used only for K in the small-ws path.
// ---------------------------------------------------------------------------
__global__ __launch_bounds__(256) void proj_k_slow(
        const float* __restrict__ A, const __bf16* __restrict__ Bt,
        const float* __restrict__ bias, __bf16* __restrict__ out) {
    __shared__ __bf16 As[128 * 72];
    __shared__ __bf16 Bs[128 * 72];
    const int t = threadIdx.x;
    const int wave = t >> 6, lane = t & 63, lm = lane & 15, quad = lane >> 4;
    const int m0 = blockIdx.y * 128, n0 = blockIdx.x * 128;
    const int wm = (wave >> 1) * 64, wn = (wave & 1) * 64;

    f32x4 acc[4][4];
#pragma unroll
    for (int i = 0; i < 4; i++)
#pragma unroll
        for (int j = 0; j < 4; j++) acc[i][j] = zero4();

    for (int k0 = 0; k0 < 1024; k0 += 64) {
#pragma unroll
        for (int i = 0; i < 4; i++) {
            int c = i * 256 + t;
            int row = c >> 3, c8 = c & 7;
            f32x8 a = *(const f32x8*)&A[(size_t)(m0 + row) * 1024 + k0 + c8 * 8];
            Bf8 tmp;
#pragma unroll
            for (int j = 0; j < 8; j++) tmp.e[j] = (__bf16)a[j];
            *(bf16x8*)&As[row * 72 + c8 * 8] = tmp.v;
            *(bf16x8*)&Bs[row * 72 + c8 * 8] =
                *(const bf16x8*)&Bt[(size_t)(n0 + row) * 1024 + k0 + c8 * 8];
        }
        __syncthreads();
#pragma unroll
        for (int ks = 0; ks < 2; ks++) {
            bf16x8 af[4], bfr[4];
#pragma unroll
            for (int mt = 0; mt < 4; mt++)
                af[mt] = *(const bf16x8*)&As[(wm + mt * 16 + lm) * 72 + ks * 32 + quad * 8];
#pragma unroll
            for (int nt = 0; nt < 4; nt++)
                bfr[nt] = *(const bf16x8*)&Bs[(wn + nt * 16 + lm) * 72 + ks * 32 + quad * 8];
#pragma unroll
            for (int mt = 0; mt < 4; mt++)
#pragma unroll
                for (int nt = 0; nt < 4; nt++)
                    acc[mt][nt] = MFMA16(af[mt], bfr[nt], acc[mt][nt], 0, 0, 0);
        }
        __syncthreads();
    }

    float bv4[4];
#pragma unroll
    for (int nt = 0; nt < 4; nt++) bv4[nt] = bias[n0 + wn + nt * 16 + lm];

#pragma unroll
    for (int mt = 0; mt < 4; mt++)
#pragma unroll
        for (int r = 0; r < 4; r++) {
            int row = m0 + wm + mt * 16 + quad * 4 + r;
#pragma unroll
            for (int nt = 0; nt < 4; nt++) {
                int col = n0 + wn + nt * 16 + lm;
                float val = acc[mt][nt][r] + bv4[nt];
                int b = row >> 11, s = row & 2047, hh = col >> 6, dk = col & 63;
                out[(size_t)(b * 16 + hh) * 131072 + (size_t)s * 64 + dk] = (__bf16)val;
            }
        }
}

// ---------------------------------------------------------------------------
// Flash attention (transposed scores), as r10 + packed-f32 softmax arith.
// ---------------------------------------------------------------------------
__global__ __launch_bounds__(256, 2) void attn_kernel(
        const __bf16* __restrict__ Q, const __bf16* __restrict__ K,
        const __bf16* __restrict__ Vt, __bf16* __restrict__ O) {
    __shared__ __bf16 Ks[8192];
    __shared__ __bf16 Vs[8192];
    __shared__ __bf16 Ps[4 * 32 * 136];
    const int t = threadIdx.x;
    const int wave = t >> 6, lane = t & 63, lm = lane & 15, quad = lane >> 4;
    const int q0 = blockIdx.x * 128;
    const int bh = blockIdx.y;
    const size_t base = (size_t)bh * 131072;

    bf16x8 bq[2][2];
    {
        int qrow = q0 + wave * 32;
#pragma unroll
        for (int nt = 0; nt < 2; nt++)
#pragma unroll
            for (int ks = 0; ks < 2; ks++)
                bq[nt][ks] = *(const bf16x8*)
                    &Q[base + (size_t)(qrow + nt * 16 + lm) * 64 + ks * 32 + quad * 8];
    }

    float m_run[2], l_run[2];
#pragma unroll
    for (int n = 0; n < 2; n++) { m_run[n] = -1e30f; l_run[n] = 0.f; }
    f32x4 o_acc[4][2];
#pragma unroll
    for (int mt = 0; mt < 4; mt++)
#pragma unroll
        for (int n = 0; n < 2; n++) o_acc[mt][n] = zero4();

    __bf16* Pw = &Ps[wave * 32 * 136];

    for (int kv0 = 0; kv0 < 2048; kv0 += 128) {
#pragma unroll
        for (int i = 0; i < 4; i++) {
            int s = i * 256 + t;
            {
                int row = s >> 3, cb = (s & 7) ^ (row & 7);
                load_lds16(&K[base + (size_t)(kv0 + row) * 64 + cb * 8],
                           &Ks[(size_t)(i * 256 + wave * 64) * 8]);
            }
            {
                int row = s >> 4, cb = (s & 15) ^ (row & 15);
                load_lds16(&Vt[base + (size_t)row * 2048 + kv0 + cb * 8],
                           &Vs[(size_t)(i * 256 + wave * 64) * 8]);
            }
        }
        __syncthreads();

        f32x4 sc[8][2];
#pragma unroll
        for (int mt = 0; mt < 8; mt++) {
            sc[mt][0] = zero4();
            sc[mt][1] = zero4();
#pragma unroll
            for (int ks = 0; ks < 2; ks++) {
                bf16x8 ak = *(const bf16x8*)&Ks[(mt * 16 + lm) * 64 +
                                                (((ks * 4 + quad) ^ (lm & 7)) * 8)];
                sc[mt][0] = MFMA16(ak, bq[0][ks], sc[mt][0], 0, 0, 0);
                sc[mt][1] = MFMA16(ak, bq[1][ks], sc[mt][1], 0, 0, 0);
            }
        }

#pragma unroll
        for (int nt = 0; nt < 2; nt++) {
            float mx = -1e30f;
#pragma unroll
            for (int mt = 0; mt < 8; mt++)
                mx = fmaxf(mx, fmaxf(fmaxf(sc[mt][nt][0], sc[mt][nt][1]),
                                     fmaxf(sc[mt][nt][2], sc[mt][nt][3])));
            mx = fmaxf(mx, __shfl_xor(mx, 16));
            mx = fmaxf(mx, __shfl_xor(mx, 32));
            float mn = fmaxf(m_run[nt], mx);
            float alpha = __expf(m_run[nt] - mn);
            m_run[nt] = mn;
            f32x4 mn4; mn4[0] = mn4[1] = mn4[2] = mn4[3] = mn;
            f32x4 su4 = zero4();
#pragma unroll
            for (int mt = 0; mt < 8; mt++) {
                f32x4 p = sc[mt][nt] - mn4;        // v_pk_add_f32
#pragma unroll
                for (int r = 0; r < 4; r++) p[r] = __expf(p[r]);
                sc[mt][nt] = p;
                su4 += p;                          // v_pk_add_f32
            }
            float su = (su4[0] + su4[1]) + (su4[2] + su4[3]);
            su += __shfl_xor(su, 16);
            su += __shfl_xor(su, 32);
            l_run[nt] = l_run[nt] * alpha + su;
            f32x4 a4; a4[0] = a4[1] = a4[2] = a4[3] = alpha;
#pragma unroll
            for (int mt = 0; mt < 4; mt++) o_acc[mt][nt] *= a4;  // v_pk_mul
        }

#pragma unroll
        for (int nt = 0; nt < 2; nt++)
#pragma unroll
            for (int mt = 0; mt < 8; mt++) {
                bf16x4 pk;
#pragma unroll
                for (int r = 0; r < 4; r++) pk[r] = (__bf16)sc[mt][nt][r];
                *(bf16x4*)&Pw[(nt * 16 + lm) * 136 + mt * 16 + quad * 4] = pk;
            }
        __asm__ volatile("" ::: "memory");

#pragma unroll
        for (int ks = 0; ks < 4; ks++) {
            bf16x8 bp[2];
#pragma unroll
            for (int nt = 0; nt < 2; nt++)
                bp[nt] = *(const bf16x8*)&Pw[(nt * 16 + lm) * 136 + ks * 32 + quad * 8];
#pragma unroll
            for (int mt = 0; mt < 4; mt++) {
                bf16x8 av = *(const bf16x8*)&Vs[(mt * 16 + lm) * 128 +
                                                (((ks * 4 + quad) ^ lm) * 8)];
                o_acc[mt][0] = MFMA16(av, bp[0], o_acc[mt][0], 0, 0, 0);
                o_acc[mt][1] = MFMA16(av, bp[1], o_acc[mt][1], 0, 0, 0);
            }
        }
        __syncthreads();
    }

#pragma unroll
    for (int nt = 0; nt < 2; nt++) {
        float inv = 1.f / l_run[nt];
#pragma unroll
        for (int mt = 0; mt < 4; mt++) {
            bf16x4 pk;
#pragma unroll
            for (int r = 0; r < 4; r++) pk[r] = (__bf16)(o_acc[mt][nt][r] * inv);
            *(bf16x4*)&Pw[(nt * 16 + lm) * 136 + mt * 16 + quad * 4] = pk;
        }
    }
    __asm__ volatile("" ::: "memory");
    {
        const int b = bh >> 4, h = bh & 15;
        int ql = lane >> 1, half = lane & 1;
        int srow = q0 + wave * 32 + ql;
#pragma unroll
        for (int j = 0; j < 4; j++) {
            bf16x8 v = *(const bf16x8*)&Pw[ql * 136 + half * 32 + j * 8];
            *(bf16x8*)&O[(size_t)(b * 2048 + srow) * 1024 + h * 64 + half * 32 + j * 8] = v;
        }
    }
}

// ---------------------------------------------------------------------------
extern "C" void kernel_launch(void* const* d_in, const int* in_sizes, int n_in,
                              void* d_out, int out_size, void* d_ws, size_t ws_size,
                              hipStream_t stream) {
    if (ws_size < ((size_t)40 << 20)) return;

    const float* query = (const float*)d_in[0];
    const float* key_  = (const float*)d_in[1];
    const float* value = (const float*)d_in[2];
    const float* wq = (const float*)d_in[3];
    const float* bq = (const float*)d_in[4];
    const float* wk = (const float*)d_in[5];
    const float* bk = (const float*)d_in[6];
    const float* wv = (const float*)d_in[7];
    const float* bv = (const float*)d_in[8];
    const float* wo = (const float*)d_in[9];
    const float* bo = (const float*)d_in[10];
    float* out = (float*)d_out;

    char* ws = (char*)d_ws;
    __bf16* WT = (__bf16*)(ws);                                   // 8 MB @0

    if (ws_size >= ((size_t)56 << 20)) {
        __bf16* Xb  = (__bf16*)(ws + ((size_t)8 << 20));          // 24 MB
        __bf16* Ow  = (__bf16*)(ws + ((size_t)8 << 20));          // alias Xb
        __bf16* Qw  = (__bf16*)(ws + ((size_t)32 << 20));
        __bf16* Kw  = (__bf16*)(ws + ((size_t)40 << 20));
        __bf16* Vtw = (__bf16*)(ws + ((size_t)48 << 20));
        prep_all<<<dim3(32, 32, 7), dim3(256), 0, stream>>>(
            wq, wk, wv, wo, query, key_, value, WT,
            Xb, Xb + 4194304, Xb + 8388608);
        proj_fast3<<<dim3(8, 32, 3), dim3(256), 0, stream>>>(
            Xb, WT, bq, bk, bv, Qw, Kw, Vtw);
        attn_kernel<<<dim3(16, 32), dim3(256), 0, stream>>>(Qw, Kw, Vtw, Ow);
        out_proj_fast<<<dim3(8, 32), dim3(256), 0, stream>>>(
            Ow, WT + 3 * 1048576, bo, out);
    } else {
        // 5-region rotation, exactly 40 MB:
        // prep: query->R1, value->R2 ; projQV: R1->R3 (Q), R2->R4 (Vt)
        // projK(slow): key(fp32)->R1 ; attn: R3,R1,R4 -> R2 ; outproj: R2->out
        __bf16* R1 = (__bf16*)(ws + ((size_t)8  << 20));
        __bf16* R2 = (__bf16*)(ws + ((size_t)16 << 20));
        __bf16* R3 = (__bf16*)(ws + ((size_t)24 << 20));
        __bf16* R4 = (__bf16*)(ws + ((size_t)32 << 20));
        prep_all<<<dim3(32, 32, 6), dim3(256), 0, stream>>>(
            wq, wk, wv, wo, query, value, (const float*)nullptr, WT,
            R1, R2, (__bf16*)nullptr);
        proj_qv<<<dim3(8, 32, 2), dim3(256), 0, stream>>>(
            R1, R2, WT, bq, bv, R3, R4);
        proj_k_slow<<<dim3(8, 32), dim3(256), 0, stream>>>(
            key_, WT + 1048576, bk, R1);
        attn_kernel<<<dim3(16, 32), dim3(256), 0, stream>>>(R3, R1, R4, R2);
        out_proj_fast<<<dim3(8, 32), dim3(256), 0, stream>>>(
            R2, WT + 3 * 1048576, bo, out);
    }
}